// Round 9
// baseline (287.395 us; speedup 1.0000x reference)
//
#include <hip/hip_runtime.h>
#include <stdint.h>

// Problem constants
#define T_SEQ 2048
#define BATCH 2
#define DIM   1024
#define NH    16
#define HD    64
#define TKP   2112   // padded key rows: keys 0..2047, prefix at 2048, zeros 2049..2111

typedef _Float16 v8h __attribute__((ext_vector_type(8)));
typedef _Float16 v4h __attribute__((ext_vector_type(4)));
typedef __fp16   pkh2 __attribute__((ext_vector_type(2)));   // cvt_pkrtz result type
typedef float    f32x4 __attribute__((ext_vector_type(4)));
typedef float    f32x16 __attribute__((ext_vector_type(16)));

// async global->LDS, 16B per lane; LDS dst must be wave-uniform base (lane*16 auto)
__device__ __forceinline__ void gload16(const _Float16* g, _Float16* l) {
  __builtin_amdgcn_global_load_lds(
      (__attribute__((address_space(1))) unsigned int*)g,
      (__attribute__((address_space(3))) unsigned int*)l, 16, 0, 0);
}

// ---------------- fused f32 -> f16 convert (q,k,v,wq,wk,wv,wo in one launch) ------
__global__ void cvt_all(const float4* __restrict__ s0, const float4* __restrict__ s1,
                        const float4* __restrict__ s2, const float4* __restrict__ s3,
                        const float4* __restrict__ s4, const float4* __restrict__ s5,
                        const float4* __restrict__ s6,
                        v4h* __restrict__ d0, v4h* __restrict__ d1, v4h* __restrict__ d2,
                        v4h* __restrict__ d3, v4h* __restrict__ d4, v4h* __restrict__ d5,
                        v4h* __restrict__ d6) {
  const int NTB4 = 1048576, DD4 = 262144;      // float4 counts
  int i = blockIdx.x * 256 + threadIdx.x;      // 0..4194303
  const float4* s; v4h* d; int off;
  if (i < 3 * NTB4) {
    int t = i / NTB4; off = i - t * NTB4;
    s = t == 0 ? s0 : t == 1 ? s1 : s2;
    d = t == 0 ? d0 : t == 1 ? d1 : d2;
  } else {
    int j = i - 3 * NTB4;
    int t = j / DD4; off = j - t * DD4;
    s = t == 0 ? s3 : t == 1 ? s4 : t == 2 ? s5 : s6;
    d = t == 0 ? d3 : t == 1 ? d4 : t == 2 ? d5 : d6;
  }
  float4 v = s[off];
  v4h o = { (_Float16)v.x, (_Float16)v.y, (_Float16)v.z, (_Float16)v.w };
  d[off] = o;
}

// ---------------- prefix MLP stage 1 + K/V pad zeroing (merged: one launch) ------
__global__ void prefix_pad_k(const float* __restrict__ wte, const float* __restrict__ w1,
                             const float* __restrict__ b1, const int* __restrict__ lang,
                             float* __restrict__ hbuf,
                             _Float16* __restrict__ kb, _Float16* __restrict__ vb) {
  if (blockIdx.x >= 400) {
    // pad part: zero key rows 2048..2111 / V cols 2048..2111 (prefix_kv_k then
    // overwrites slot 2048). Contiguous 16B stores.
    int bh = blockIdx.x - 400;
    v8h z = {};
    _Float16* kp = kb + ((size_t)bh * TKP + 2048) * 64;    // 64 rows x 64 = contiguous
    for (int i = threadIdx.x; i < 512; i += 256) *(v8h*)&kp[i * 8] = z;
    for (int i = threadIdx.x; i < 512; i += 256) {         // 64 hd-rows x 64 t, 8 segs
      int c = i >> 3, seg = i & 7;
      *(v8h*)&vb[((size_t)bh * 64 + c) * TKP + 2048 + seg * 8] = z;
    }
    return;
  }
  int wid = blockIdx.x * 4 + (threadIdx.x >> 6);   // 0..1599 = b*800+j
  int lane = threadIdx.x & 63;
  int b = wid / 800, j = wid - b * 800;
  int c = lang[b];
  const float* wr = w1 + ((size_t)c * 800 + j) * 1024;
  const float* em = wte + (size_t)c * 1024;
  float s = 0.f;
  for (int d = lane; d < 1024; d += 64) s += wr[d] * em[d];
  for (int off = 32; off > 0; off >>= 1) s += __shfl_down(s, off, 64);
  if (lane == 0) hbuf[wid] = tanhf(s + b1[c * 800 + j]);
}

// kv[b,e]: e<1024 -> prefix K (key slot 2048), else prefix V (col slot 2048)
__global__ void prefix_kv_k(const float* __restrict__ w2, const float* __restrict__ b2,
                            const float* __restrict__ hbuf, const int* __restrict__ lang,
                            _Float16* __restrict__ kb, _Float16* __restrict__ vb) {
  int wid = blockIdx.x * 4 + (threadIdx.x >> 6);   // 0..4095 = b*2048+e
  int lane = threadIdx.x & 63;
  int b = wid >> 11, e = wid & 2047;
  int c = lang[b];
  const float* wr = w2 + ((size_t)c * 2048 + e) * 800;
  const float* hb = hbuf + b * 800;
  float s = 0.f;
  for (int j = lane; j < 800; j += 64) s += wr[j] * hb[j];
  for (int off = 32; off > 0; off >>= 1) s += __shfl_down(s, off, 64);
  if (lane == 0) {
    float val = s + b2[c * 2048 + e];
    if (e < 1024) {
      int h = e >> 6, hd = e & 63;
      kb[((size_t)(b * 16 + h) * TKP + 2048) * 64 + hd] = (_Float16)val;
    } else {
      int d = e - 1024;
      int h = d >> 6, hd = d & 63;
      vb[((size_t)(b * 16 + h) * 64 + hd) * TKP + 2048] = (_Float16)val;
    }
  }
}

// ---------------- gemm_bt: Out[r,e] = sum_d A[r,d]*W[e,d] + bias[e] ----------------
// 128x128 tile, BK=64, 4 waves 2x2, 16x16x32 f16 MFMA.
// v7 K-loop: double-buffered LDS (64KB) + issue-ahead staging, raw s_barrier +
// counted "s_waitcnt vmcnt(8)" (never 0 in-loop) so the next step's 8 loads stay
// in flight under compute; T2 XOR-swizzle (pre-swizzled GLOBAL source segment,
// linear LDS dest for global_load_lds; reads use slot^(l15&7)).
// mode 0: q (*0.125*log2e -> [B,H,T,hd]); 1: k (-> [B,H,t,hd], prefix at 2048);
// mode 2: v transposed (-> [B,H,hd,t]); 3: fp32 out (d_out [T,B,D], direct stores)
__global__ __launch_bounds__(256) void gemm_bt_k(
    const _Float16* __restrict__ A0, const _Float16* __restrict__ A1, const _Float16* __restrict__ A2,
    const _Float16* __restrict__ W0, const _Float16* __restrict__ W1, const _Float16* __restrict__ W2,
    const float* __restrict__ bs0, const float* __restrict__ bs1, const float* __restrict__ bs2,
    _Float16* __restrict__ qb, _Float16* __restrict__ kb, _Float16* __restrict__ vb,
    float* __restrict__ fout, int mode_base)
{
  __shared__ __align__(16) _Float16 smem[2][128 * 64 * 2];   // [buf][As|Bs]
  const int mode = mode_base + blockIdx.z;
  const _Float16* A = (mode == 1) ? A1 : (mode == 2) ? A2 : A0;
  const _Float16* W = (mode == 1) ? W1 : (mode == 2) ? W2 : W0;
  const float* bias = (mode == 1) ? bs1 : (mode == 2) ? bs2 : bs0;
  const int tid = threadIdx.x, w = tid >> 6, lane = tid & 63;
  const int quad = lane >> 4, l15 = lane & 15;
  const int r0 = blockIdx.x * 128, c0 = blockIdx.y * 128;
  const int wm = w >> 1, wn = w & 1;
  const int srow = lane >> 3, sseg = lane & 7;   // srow 0..7, sseg 0..7
  const int sw_seg = sseg ^ srow;                // pre-swizzled global segment
  const int rsw = l15 & 7;                       // read-side row-XOR
  f32x4 acc[4][4] = {};

  // stage K-step tile k0 into buffer p (8 gload_lds per wave)
  auto stage = [&](int k0, int p) {
    _Float16* As = smem[p];
    _Float16* Bs = smem[p] + 8192;
#pragma unroll
    for (int i = 0; i < 4; ++i) {
      int rowb = w * 32 + i * 8;
      gload16(A + (size_t)(r0 + rowb + srow) * 1024 + k0 + sw_seg * 8, &As[rowb * 64]);
      gload16(W + (size_t)(c0 + rowb + srow) * 1024 + k0 + sw_seg * 8, &Bs[rowb * 64]);
    }
  };

  stage(0, 0);                                   // prologue: 8 outstanding
  for (int t = 0; t < 16; ++t) {
    if (t < 15) {
      stage((t + 1) << 6, (t + 1) & 1);          // 16 outstanding
      asm volatile("s_waitcnt vmcnt(8)" ::: "memory");   // wait ONLY step t's 8
    } else {
      asm volatile("s_waitcnt vmcnt(0)" ::: "memory");
    }
    __builtin_amdgcn_s_barrier();                // all waves' buf[t] complete
    __builtin_amdgcn_sched_barrier(0);
    const _Float16* As = smem[t & 1];
    const _Float16* Bs = smem[t & 1] + 8192;
#pragma unroll
    for (int ks = 0; ks < 2; ++ks) {
      v8h af[4], bfr[4];
#pragma unroll
      for (int mt = 0; mt < 4; ++mt)
        af[mt] = *(const v8h*)&As[(wm * 64 + mt * 16 + l15) * 64 + (((ks * 4 + quad) ^ rsw) * 8)];
#pragma unroll
      for (int nt = 0; nt < 4; ++nt)
        bfr[nt] = *(const v8h*)&Bs[(wn * 64 + nt * 16 + l15) * 64 + (((ks * 4 + quad) ^ rsw) * 8)];
#pragma unroll
      for (int mt = 0; mt < 4; ++mt)
#pragma unroll
        for (int nt = 0; nt < 4; ++nt)
          acc[mt][nt] = __builtin_amdgcn_mfma_f32_16x16x32_f16(af[mt], bfr[nt], acc[mt][nt], 0, 0, 0);
    }
    __builtin_amdgcn_sched_barrier(0);
    __builtin_amdgcn_s_barrier();                // reads of buf[t] done before its next DMA
  }
  // ---- epilogue; C/D layout: col = lane&15, row = quad*4 + reg ----
  if (mode == 3) {
    // fp32 direct: 16 l15-lanes x 4B = one full 64B line per quad. Already ideal.
    for (int nt = 0; nt < 4; ++nt) {
      int e = c0 + wn * 64 + nt * 16 + l15;
      float be = bias[e];
      for (int mt = 0; mt < 4; ++mt) {
        int rb = r0 + wm * 64 + mt * 16 + quad * 4;
        for (int reg = 0; reg < 4; ++reg)
          fout[(size_t)(rb + reg) * 1024 + e] = acc[mt][nt][reg] + be;
      }
    }
    return;
  }
  _Float16* st = &smem[0][0] + w * 4096;         // wave-private stage (8192 B)
  // mode 0: fold softmax's log2(e) into the Q scale so attn can use raw v_exp_f32
  const float qscale = (mode == 0) ? 0.125f * 1.44269504088896341f : 1.0f;
  for (int p = 0; p < 2; ++p) {                  // pass = half of the e-range (32 cols)
    __syncthreads();
    for (int ntl = 0; ntl < 2; ++ntl) {
      int nt = p * 2 + ntl;
      int e = c0 + wn * 64 + nt * 16 + l15;
      float be = bias[e];
      for (int mt = 0; mt < 4; ++mt)
        for (int reg = 0; reg < 4; ++reg) {
          float val = (acc[mt][nt][reg] + be) * qscale;
          int rl = mt * 16 + quad * 4 + reg;     // 0..63 local row
          if (mode != 2) st[rl * 40 + ntl * 16 + l15] = (_Float16)val;       // stride 40: 80B, 16B-mult
          else st[(ntl * 16 + l15) * 72 + (rl & 1) * 32 + (rl >> 1)] = (_Float16)val;  // stride 72: 144B
        }
    }
    __syncthreads();
    if (mode != 2) {
      // st[row r (64)][e (32), stride 40]; 4-lane groups write full 64B lines
      for (int it = 0; it < 4; ++it) {
        int chunk = it * 64 + lane;              // 0..255
        int rr = chunk >> 2, seg = chunk & 3;
        v8h val = *(const v8h*)&st[rr * 40 + seg * 8];
        int r = r0 + wm * 64 + rr, b = r & 1, t = r >> 1;
        int e0 = c0 + wn * 64 + p * 32 + seg * 8;
        int h = e0 >> 6, hd0 = e0 & 63;
        if (mode == 0) *(v8h*)&qb[((size_t)(b * 16 + h) * 2048 + t) * 64 + hd0] = val;
        else           *(v8h*)&kb[((size_t)(b * 16 + h) * TKP + t) * 64 + hd0] = val;
      }
    } else {
      // st[e (32), stride 72][b(2)*32 + t(32)]; 4-lane groups write full 64B lines
      for (int it = 0; it < 4; ++it) {
        int chunk = it * 64 + lane;              // 0..255
        int el = chunk >> 3, b = (chunk >> 2) & 1, qs = chunk & 3;
        v8h val = *(const v8h*)&st[el * 72 + b * 32 + qs * 8];
        int e = c0 + wn * 64 + p * 32 + el;
        int h = e >> 6, hd = e & 63;
        int t0 = ((r0 + wm * 64) >> 1) + qs * 8;
        *(v8h*)&vb[((size_t)(b * 16 + h) * 64 + hd) * TKP + t0] = val;
      }
    }
  }
}

// ---------------- flash attention (v9: KC=128 main loop + 64-key epilogue) --------
// v8b counters: MfmaUtil 38, VALUBusy 35, conflicts 0, occupancy 16.6% (grid =
// exactly 2 blocks/CU = 2 waves/SIMD). Neither pipe saturated -> remaining ~27%
// is the serial QK->exp->PV dependency chain + 33 barrier resyncs.
// v9: 128 keys per barrier-iteration (16 iters, no masking -- all real keys) +
// one 64-key masked epilogue for prefix/pad (2048..2111). Doubles in-iteration
// ILP (4 independent S-tile MFMA chains; 8-chunk PV stream lets exp/pack of
// chunk c+1 overlap MFMAs of chunk c), halves barrier count.
// LDS 70KB (2 blocks/CU still); VGPR grows but grid caps occupancy anyway ->
// __launch_bounds__(256,1) frees the allocator.
// PV stays no-exchange: key(c,hi,j) = c*16 + (j&3) + 8*(j>>2) + 4*hi, V staged
// with matching sigma permutation (two 8B writes per 16B chunk).
__global__ __launch_bounds__(256, 1) void attn_k(
    const _Float16* __restrict__ qb, const _Float16* __restrict__ kb,
    const _Float16* __restrict__ vb, _Float16* __restrict__ ctx)
{
  __shared__ __align__(16) _Float16 Ks[2][128 * 72];   // 36864 B
  __shared__ __align__(16) _Float16 Vs[2][64 * 136];   // 34816 B
  const int bh = blockIdx.x;
  const int qt0 = blockIdx.y * 128;
  const int tid = threadIdx.x, w = tid >> 6, lane = tid & 63;
  const int l31 = lane & 31, h8 = (lane >> 5) * 8;
  // loop-invariant Q fragments (B-operand, 32x32x16): n = l31 (query), k = t*16+h8+j
  v8h qf[4];
#pragma unroll
  for (int t = 0; t < 4; ++t)
    qf[t] = *(const v8h*)(qb + ((size_t)bh * 2048 + qt0 + w * 32 + l31) * 64 + t * 16 + h8);
  // staging coords: K row = sr + 32j (j=0..3); V hd-row = sr + 32j (j=0..1), key grp g
  const int sr = tid >> 3, sseg = tid & 7;
  const _Float16* kptr = kb + (size_t)bh * TKP * 64 + sr * 64 + sseg * 8;
  const _Float16* vptr = vb + (size_t)bh * 64 * TKP + (size_t)sr * TKP + sseg * 8;
  // sigma staging byte-col within a 64-key group: keys sseg*8..+3 -> chunk
  // c=sseg>>1 half (sseg&1): col = c*32+(sseg&1)*8; keys +4..+7 -> col+16.
  const int vcb = (sseg >> 1) * 32 + (sseg & 1) * 8;
  int4 kp[4], vp[4];
#pragma unroll
  for (int j = 0; j < 4; ++j) kp[j] = *(const int4*)(kptr + j * 2048);
#pragma unroll
  for (int j = 0; j < 2; ++j)
#pragma unroll
    for (int g = 0; g < 2; ++g)
      vp[j * 2 + g] = *(const int4*)(vptr + (size_t)j * 32 * TKP + g * 64);
  kptr += 8192; vptr += 128;
  const v8h vones = { (_Float16)1.f, (_Float16)1.f, (_Float16)1.f, (_Float16)1.f,
                      (_Float16)1.f, (_Float16)1.f, (_Float16)1.f, (_Float16)1.f };
  f32x16 O0 = {}, O1 = {}, lacc = {};
  for (int kc = 0; kc < 16; ++kc) {
    _Float16* Kb = Ks[kc & 1];
    _Float16* Vb = Vs[kc & 1];
    // write chunk kc; parity + 1 barrier/iter keeps buffer reuse race-free
#pragma unroll
    for (int j = 0; j < 4; ++j)
      *(int4*)&Kb[(sr + 32 * j) * 72 + sseg * 8] = kp[j];
#pragma unroll
    for (int j = 0; j < 2; ++j)
#pragma unroll
      for (int g = 0; g < 2; ++g) {
        char* vr = (char*)&Vb[(sr + 32 * j) * 136] + g * 128 + vcb;
        *(int2*)(vr)      = *(int2*)&vp[j * 2 + g];
        *(int2*)(vr + 16) = *((int2*)&vp[j * 2 + g] + 1);
      }
    __syncthreads();
    if (kc < 15) {                               // prefetch next 128-key chunk
#pragma unroll
      for (int j = 0; j < 4; ++j) kp[j] = *(const int4*)(kptr + j * 2048);
#pragma unroll
      for (int j = 0; j < 2; ++j)
#pragma unroll
        for (int g = 0; g < 2; ++g)
          vp[j * 2 + g] = *(const int4*)(vptr + (size_t)j * 32 * TKP + g * 64);
      kptr += 8192; vptr += 128;
    } else {                                     // prefetch 64-key epilogue chunk
      kp[0] = *(const int4*)kptr;                // key rows 2048+sr
      kp[1] = *(const int4*)(kptr + 2048);       // 2048+sr+32
      vp[0] = *(const int4*)vptr;                // V cols 2048.., hd rows sr / sr+32
      vp[1] = *(const int4*)(vptr + (size_t)32 * TKP);
    }
    // S^T = K(128keys x 64d) . Q^T: four 32x32 key tiles, 4 k-steps of 16
    f32x16 S[4] = { {}, {}, {}, {} };
    __builtin_amdgcn_s_setprio(1);
#pragma unroll
    for (int t = 0; t < 4; ++t) {
#pragma unroll
      for (int j = 0; j < 4; ++j) {
        v8h kf = *(const v8h*)&Kb[(32 * j + l31) * 72 + t * 16 + h8];
        S[j] = __builtin_amdgcn_mfma_f32_32x32x16_f16(kf, qf[t], S[j], 0, 0, 0);
      }
    }
    // P = exp2(S) fused into v_cvt_pkrtz packs; PV + denominator via MFMA.
#pragma unroll
    for (int c = 0; c < 8; ++c) {
      const int b0 = (c & 1) * 8;
      union { v8h v; pkh2 p[4]; } f;
      f.p[0] = __builtin_amdgcn_cvt_pkrtz(__builtin_amdgcn_exp2f(S[c >> 1][b0 + 0]),
                                          __builtin_amdgcn_exp2f(S[c >> 1][b0 + 1]));
      f.p[1] = __builtin_amdgcn_cvt_pkrtz(__builtin_amdgcn_exp2f(S[c >> 1][b0 + 2]),
                                          __builtin_amdgcn_exp2f(S[c >> 1][b0 + 3]));
      f.p[2] = __builtin_amdgcn_cvt_pkrtz(__builtin_amdgcn_exp2f(S[c >> 1][b0 + 4]),
                                          __builtin_amdgcn_exp2f(S[c >> 1][b0 + 5]));
      f.p[3] = __builtin_amdgcn_cvt_pkrtz(__builtin_amdgcn_exp2f(S[c >> 1][b0 + 6]),
                                          __builtin_amdgcn_exp2f(S[c >> 1][b0 + 7]));
      v8h vf0 = *(const v8h*)&Vb[(l31) * 136 + c * 16 + h8];
      v8h vf1 = *(const v8h*)&Vb[(32 + l31) * 136 + c * 16 + h8];
      O0 = __builtin_amdgcn_mfma_f32_32x32x16_f16(vf0, f.v, O0, 0, 0, 0);
      O1 = __builtin_amdgcn_mfma_f32_32x32x16_f16(vf1, f.v, O1, 0, 0, 0);
      lacc = __builtin_amdgcn_mfma_f32_32x32x16_f16(vones, f.v, lacc, 0, 0, 0);
    }
    __builtin_amdgcn_s_setprio(0);
  }
  // ---- 64-key epilogue: prefix (local key 0, valid) + pad keys (masked) ----
  {
    _Float16* Kb = Ks[0];
    _Float16* Vb = Vs[0];
    *(int4*)&Kb[sr * 72 + sseg * 8] = kp[0];
    *(int4*)&Kb[(sr + 32) * 72 + sseg * 8] = kp[1];
#pragma unroll
    for (int j = 0; j < 2; ++j) {
      char* vr = (char*)&Vb[(sr + 32 * j) * 136] + vcb;
      *(int2*)(vr)      = *(int2*)&vp[j];
      *(int2*)(vr + 16) = *((int2*)&vp[j] + 1);
    }
    __syncthreads();
    f32x16 S0 = {}, S1 = {};
    __builtin_amdgcn_s_setprio(1);
#pragma unroll
    for (int t = 0; t < 4; ++t) {
      v8h kf0 = *(const v8h*)&Kb[(l31) * 72 + t * 16 + h8];
      v8h kf1 = *(const v8h*)&Kb[(32 + l31) * 72 + t * 16 + h8];
      S0 = __builtin_amdgcn_mfma_f32_32x32x16_f16(kf0, qf[t], S0, 0, 0, 0);
      S1 = __builtin_amdgcn_mfma_f32_32x32x16_f16(kf1, qf[t], S1, 0, 0, 0);
    }
    __builtin_amdgcn_s_setprio(0);
    // mask: only local key 0 (tile0, hi=0, reg0) is the valid prefix key
#pragma unroll
    for (int r = 0; r < 16; ++r) {
      if (r > 0) S0[r] = -1e30f;
      S1[r] = -1e30f;
    }
    if (lane >= 32) S0[0] = -1e30f;
    __builtin_amdgcn_s_setprio(1);
#pragma unroll
    for (int c = 0; c < 4; ++c) {
      const int b0 = (c & 1) * 8;
      union { v8h v; pkh2 p[4]; } f;
      const f32x16& Sx = (c < 2) ? S0 : S1;
      f.p[0] = __builtin_amdgcn_cvt_pkrtz(__builtin_amdgcn_exp2f(Sx[b0 + 0]),
                                          __builtin_amdgcn_exp2f(Sx[b0 + 1]));
      f.p[1] = __builtin_amdgcn_cvt_pkrtz(__builtin_amdgcn_exp2f(Sx[b0 + 2]),
                                          __builtin_amdgcn_exp2f(Sx[b0 + 3]));
      f.p[2] = __builtin_amdgcn_cvt_pkrtz(__builtin_amdgcn_exp2f(Sx[b0 + 4]),
                                          __builtin_amdgcn_exp2f(Sx[b0 + 5]));
      f.p[3] = __builtin_amdgcn_cvt_pkrtz(__builtin_amdgcn_exp2f(Sx[b0 + 6]),
                                          __builtin_amdgcn_exp2f(Sx[b0 + 7]));
      v8h vf0 = *(const v8h*)&Vb[(l31) * 136 + c * 16 + h8];
      v8h vf1 = *(const v8h*)&Vb[(32 + l31) * 136 + c * 16 + h8];
      O0 = __builtin_amdgcn_mfma_f32_32x32x16_f16(vf0, f.v, O0, 0, 0, 0);
      O1 = __builtin_amdgcn_mfma_f32_32x32x16_f16(vf1, f.v, O1, 0, 0, 0);
      lacc = __builtin_amdgcn_mfma_f32_32x32x16_f16(vones, f.v, lacc, 0, 0, 0);
    }
    __builtin_amdgcn_s_setprio(0);
  }
  // lacc rows all equal the per-query-column denominator (summed over ALL keys,
  // both lane halves included via the B fragment) -> no cross-lane reduce.
  const float inv = 1.f / lacc[0];
  const int b = bh >> 4, hh = bh & 15;
  const int q = qt0 + w * 32 + l31;
  _Float16* cbase = ctx + ((size_t)q * 2 + b) * 1024 + hh * 64 + (h8 >> 1);  // +4*hi
#pragma unroll
  for (int rq = 0; rq < 4; ++rq) {
    v4h o0 = { (_Float16)(O0[rq * 4 + 0] * inv), (_Float16)(O0[rq * 4 + 1] * inv),
               (_Float16)(O0[rq * 4 + 2] * inv), (_Float16)(O0[rq * 4 + 3] * inv) };
    *(v4h*)(cbase + rq * 8) = o0;
    v4h o1 = { (_Float16)(O1[rq * 4 + 0] * inv), (_Float16)(O1[rq * 4 + 1] * inv),
               (_Float16)(O1[rq * 4 + 2] * inv), (_Float16)(O1[rq * 4 + 3] * inv) };
    *(v4h*)(cbase + 32 + rq * 8) = o1;
  }
}

extern "C" void kernel_launch(void* const* d_in, const int* in_sizes, int n_in,
                              void* d_out, int out_size, void* d_ws, size_t ws_size,
                              hipStream_t stream) {
  (void)in_sizes; (void)n_in; (void)out_size; (void)ws_size;
  const float* query = (const float*)d_in[0];
  const float* key_  = (const float*)d_in[1];
  const float* value = (const float*)d_in[2];
  const float* wq = (const float*)d_in[3];
  const float* bq = (const float*)d_in[4];
  const float* wk = (const float*)d_in[5];
  const float* bk = (const float*)d_in[6];
  const float* wv = (const float*)d_in[7];
  const float* bv = (const float*)d_in[8];
  const float* wo = (const float*)d_in[9];
  const float* bo = (const float*)d_in[10];
  const float* wte = (const float*)d_in[11];
  const float* w1 = (const float*)d_in[12];
  const float* b1 = (const float*)d_in[13];
  const float* w2 = (const float*)d_in[14];
  const float* b2 = (const float*)d_in[15];
  const int* lang = (const int*)d_in[16];
  float* out = (float*)d_out;

  const size_t NTB = (size_t)T_SEQ * BATCH * DIM;   // 4194304
  const size_t DD  = (size_t)DIM * DIM;             // 1048576
  const size_t KVN = (size_t)BATCH * NH * TKP * HD; // 4325376
  _Float16* xq  = (_Float16*)d_ws;
  _Float16* xk  = xq + NTB;
  _Float16* xv  = xk + NTB;
  _Float16* wqb = xv + NTB;
  _Float16* wkb = wqb + DD;
  _Float16* wvb = wkb + DD;
  _Float16* wob = wvb + DD;
  _Float16* qbuf = wob + DD;
  _Float16* kbuf = qbuf + NTB;
  _Float16* vbuf = kbuf + KVN;
  float* hbuf = (float*)(vbuf + KVN);
  _Float16* ctxb = xq;   // alias: xq is dead after the QKV projections

  cvt_all<<<16384, 256, 0, stream>>>((const float4*)query, (const float4*)key_,
                                     (const float4*)value, (const float4*)wq,
                                     (const float4*)wk, (const float4*)wv, (const float4*)wo,
                                     (v4h*)xq, (v4h*)xk, (v4h*)xv, (v4h*)wqb,
                                     (v4h*)wkb, (v4h*)wvb, (v4h*)wob);
  prefix_pad_k<<<432, 256, 0, stream>>>(wte, w1, b1, lang, hbuf, kbuf, vbuf);
  prefix_kv_k<<<1024, 256, 0, stream>>>(w2, b2, hbuf, lang, kbuf, vbuf);
  gemm_bt_k<<<dim3(32, 8, 3), 256, 0, stream>>>(xq, xk, xv, wqb, wkb, wvb, bq, bk, bv,
                                                qbuf, kbuf, vbuf, nullptr, 0);
  attn_k<<<dim3(32, 16), 256, 0, stream>>>(qbuf, kbuf, vbuf, ctxb);
  gemm_bt_k<<<dim3(32, 8, 1), 256, 0, stream>>>(ctxb, ctxb, ctxb, wob, wob, wob, bo, bo, bo,
                                                qbuf, kbuf, vbuf, out, 3);
}